// Round 6
// baseline (489.549 us; speedup 1.0000x reference)
//
#include <hip/hip_runtime.h>

#define BATCH 4096
#define NAG   8
#define OBS   64
#define HD    64
#define GH    128
#define NACT  16
#define TAU   0.05f
#define CAP   65536

typedef short  bf16x8 __attribute__((ext_vector_type(8)));
typedef unsigned short u16x8 __attribute__((ext_vector_type(8)));
typedef float  f32x4  __attribute__((ext_vector_type(4)));

// ============================================================ helpers
__device__ __forceinline__ float fast_sigmoid(float x) {
    return 1.f / (1.f + __expf(-x));
}
__device__ __forceinline__ float fast_tanh(float x) {
    x = fminf(fmaxf(x, -15.f), 15.f);
    const float e = __expf(2.f * x);
    return (e - 1.f) / (e + 1.f);
}
__device__ __forceinline__ unsigned short f2bf(float f) {   // RNE f32->bf16
    unsigned int u = __builtin_bit_cast(unsigned int, f);
    u = (u + 0x7FFFu + ((u >> 16) & 1u)) >> 16;
    return (unsigned short)u;
}

// ============================================================ counter zero
__global__ void zero_counter(int* c) { if (threadIdx.x == 0) c[0] = 0; }

// ============================================================ Wi -> bf16, gate-permuted
// out gate index g' = cg*48 + s*16 + cl  <- src gate g = s*128 + cg*16 + cl.
__global__ __launch_bounds__(256) void wiconv_kernel(
    const float* __restrict__ Wi, unsigned short* __restrict__ wib)
{
    const int t   = blockIdx.x * 256 + threadIdx.x;   // 0..344063
    const int pp  = t / 6144;                         // 56 off-diag pairs
    const int rem = t - pp * 6144;
    const int gp  = rem >> 4;                         // 0..383
    const int k8  = rem & 15;                         // 8-elem chunk along k
    const int pi  = pp / 7;
    int pj = pp % 7; pj += (pj >= pi);
    const int pb  = pi * NAG + pj;
    const int cg  = gp / 48;
    const int r2  = gp - cg * 48;
    const int s   = r2 >> 4, cl = r2 & 15;
    const int g   = s * GH + cg * 16 + cl;
    const float* src = Wi + ((size_t)pb * 384 + g) * GH + k8 * 8;
    u16x8 o;
#pragma unroll
    for (int e = 0; e < 8; ++e) o[e] = f2bf(src[e]);
    *reinterpret_cast<u16x8*>(wib + ((size_t)pb * 384 + gp) * GH + k8 * 8) = o;
}

// ============================================================ A: encode (+ bf16 mirror)
__global__ __launch_bounds__(256, 2) void encode_kernel(
    const float* __restrict__ obs, const float* __restrict__ W1,
    const float* __restrict__ b1, const float* __restrict__ W2,
    const float* __restrict__ b2, float* __restrict__ h,
    unsigned short* __restrict__ hb)
{
    const int n    = blockIdx.x >> 6;
    const int tile = blockIdx.x & 63;
    const int b0   = tile * 64;
    const int tid  = threadIdx.x;

    __shared__ float u1[OBS * 68];
    __shared__ float h1t[GH * 68];
    __shared__ float wl[16 * GH];

    const float* __restrict__ W1n = W1 + n * (OBS * GH);
    const float* __restrict__ W2n = W2 + n * (GH * HD);
    const float* __restrict__ b1n = b1 + n * GH;
    const float* __restrict__ b2n = b2 + n * HD;

    {
        const int c  = tid & 63;
        const int r0 = tid >> 6;
        for (int rr = 0; rr < 16; ++rr) {
            const int bb = r0 * 16 + rr;
            u1[c * 68 + bb] = obs[((size_t)(b0 + bb) * NAG + n) * OBS + c];
        }
    }

    const int bq = tid & 15;
    const int cg = tid >> 4;

    float acc1[8][4];
#pragma unroll
    for (int cc = 0; cc < 8; ++cc)
#pragma unroll
        for (int bb = 0; bb < 4; ++bb) acc1[cc][bb] = 0.f;

    for (int kc = 0; kc < 4; ++kc) {
        __syncthreads();
#pragma unroll
        for (int p = 0; p < 2; ++p) {
            const int f = tid + p * 256;
            const int k = f >> 5, c4 = f & 31;
            *reinterpret_cast<float4*>(&wl[k * GH + c4 * 4]) =
                *reinterpret_cast<const float4*>(&W1n[(kc * 16 + k) * GH + c4 * 4]);
        }
        __syncthreads();
#pragma unroll 2
        for (int k = 0; k < 16; ++k) {
            const float4 uu = *reinterpret_cast<const float4*>(
                &u1[(kc * 16 + k) * 68 + bq * 4]);
            const float ub[4] = {uu.x, uu.y, uu.z, uu.w};
            const float4 wa = *reinterpret_cast<const float4*>(&wl[k * GH + cg * 8]);
            const float4 wb = *reinterpret_cast<const float4*>(&wl[k * GH + cg * 8 + 4]);
            const float wv[8] = {wa.x, wa.y, wa.z, wa.w, wb.x, wb.y, wb.z, wb.w};
#pragma unroll
            for (int cc = 0; cc < 8; ++cc)
#pragma unroll
                for (int bb = 0; bb < 4; ++bb)
                    acc1[cc][bb] += wv[cc] * ub[bb];
        }
    }

    {
        const float4 ba  = *reinterpret_cast<const float4*>(&b1n[cg * 8]);
        const float4 bb4 = *reinterpret_cast<const float4*>(&b1n[cg * 8 + 4]);
        const float bv[8] = {ba.x, ba.y, ba.z, ba.w, bb4.x, bb4.y, bb4.z, bb4.w};
#pragma unroll
        for (int cc = 0; cc < 8; ++cc)
#pragma unroll
            for (int bb = 0; bb < 4; ++bb)
                h1t[(cg * 8 + cc) * 68 + bq * 4 + bb] =
                    fmaxf(acc1[cc][bb] + bv[cc], 0.f);
    }

    const int og = tid >> 4;
    float acc2[4][4];
#pragma unroll
    for (int oc = 0; oc < 4; ++oc)
#pragma unroll
        for (int bb = 0; bb < 4; ++bb) acc2[oc][bb] = 0.f;

    for (int kc = 0; kc < 8; ++kc) {
        __syncthreads();
        {
            const int k = tid >> 4, o4 = tid & 15;
            *reinterpret_cast<float4*>(&wl[k * HD + o4 * 4]) =
                *reinterpret_cast<const float4*>(&W2n[(kc * 16 + k) * HD + o4 * 4]);
        }
        __syncthreads();
#pragma unroll 2
        for (int k = 0; k < 16; ++k) {
            const float4 uu = *reinterpret_cast<const float4*>(
                &h1t[(kc * 16 + k) * 68 + bq * 4]);
            const float ub[4] = {uu.x, uu.y, uu.z, uu.w};
            const float4 wa = *reinterpret_cast<const float4*>(&wl[k * HD + og * 4]);
            const float wv[4] = {wa.x, wa.y, wa.z, wa.w};
#pragma unroll
            for (int oc = 0; oc < 4; ++oc)
#pragma unroll
                for (int bb = 0; bb < 4; ++bb)
                    acc2[oc][bb] += wv[oc] * ub[bb];
        }
    }

    {
        const float4 b2v = *reinterpret_cast<const float4*>(&b2n[og * 4]);
#pragma unroll
        for (int bb = 0; bb < 4; ++bb) {
            float4 o;
            o.x = fmaxf(acc2[0][bb] + b2v.x, 0.f);
            o.y = fmaxf(acc2[1][bb] + b2v.y, 0.f);
            o.z = fmaxf(acc2[2][bb] + b2v.z, 0.f);
            o.w = fmaxf(acc2[3][bb] + b2v.w, 0.f);
            const size_t row = (size_t)(b0 + bq * 4 + bb) * NAG + n;
            *reinterpret_cast<float4*>(&h[row * HD + og * 4]) = o;
            ushort4 hv;
            hv.x = f2bf(o.x); hv.y = f2bf(o.y); hv.z = f2bf(o.z); hv.w = f2bf(o.w);
            *reinterpret_cast<ushort4*>(&hb[row * HD + og * 4]) = hv;
        }
    }
}

// ============================================================ B: pairwise GRU via MFMA
// (unchanged from R5 — validated: absmax held at 0.0078, no gate flips)
__global__ __launch_bounds__(256, 2) void pair_mfma_kernel(
    const unsigned short* __restrict__ hb, const unsigned short* __restrict__ wib,
    const float* __restrict__ bi, const float* __restrict__ bh,
    const float* __restrict__ Wg, const float* __restrict__ bg,
    const float* __restrict__ gum, float* __restrict__ wout,
    int* __restrict__ list, int* __restrict__ counter)
{
    const int pairp = blockIdx.x >> 6;
    const int tile  = blockIdx.x & 63;
    const int pi = pairp / 7;
    int pj = pairp % 7; pj += (pj >= pi);
    const int pb = pi * NAG + pj;
    const int b0 = tile * 64;

    const int tid = threadIdx.x;
    const int w   = tid >> 6;          // wave 0..3
    const int l   = tid & 63;
    const int cl  = l & 15;            // A: batch row offset / B,D: column
    const int rg  = l >> 4;            // k-chunk group / D row group

    f32x4 acc[4][6];
#pragma unroll
    for (int bt = 0; bt < 4; ++bt)
#pragma unroll
        for (int t = 0; t < 6; ++t) acc[bt][t] = (f32x4){0.f, 0.f, 0.f, 0.f};

#pragma unroll
    for (int kb = 0; kb < 4; ++kb) {
        const int ag = (kb < 2) ? pi : pj;          // u = [h_i ; h_j]
        const int ch = (kb & 1) * 32 + rg * 8;      // channel chunk within agent
        bf16x8 av[4];
#pragma unroll
        for (int bt = 0; bt < 4; ++bt) {
            const int b = b0 + bt * 16 + cl;
            av[bt] = *reinterpret_cast<const bf16x8*>(
                &hb[((size_t)b * NAG + ag) * HD + ch]);
        }
        const size_t wbase = ((size_t)pb * 384 + w * 96 + cl) * GH + kb * 32 + rg * 8;
#pragma unroll
        for (int t = 0; t < 6; ++t) {
            const bf16x8 bv = *reinterpret_cast<const bf16x8*>(
                &wib[wbase + (size_t)t * 16 * GH]);
#pragma unroll
            for (int bt = 0; bt < 4; ++bt)
                acc[bt][t] = __builtin_amdgcn_mfma_f32_16x16x32_bf16(
                    av[bt], bv, acc[bt][t], 0, 0, 0);
        }
    }

    // ---- GRU epilogue: t = cgl*3 + s; channel c = (2w+cgl)*16 + cl ----
    __shared__ float part[64][68];
    float pl[4][4];
#pragma unroll
    for (int bt = 0; bt < 4; ++bt)
#pragma unroll
        for (int r = 0; r < 4; ++r) pl[bt][r] = 0.f;

#pragma unroll
    for (int cgl = 0; cgl < 2; ++cgl) {
        const int c = (2 * w + cgl) * 16 + cl;
        const float bir = bi[pb * 384 + c];
        const float biz = bi[pb * 384 + 128 + c];
        const float bin = bi[pb * 384 + 256 + c];
        const float bhr = bh[pb * 384 + c];
        const float bhz = bh[pb * 384 + 128 + c];
        const float bhn = bh[pb * 384 + 256 + c];
        const float dwg = Wg[pb * 256 + 128 + c] - Wg[pb * 256 + c];
#pragma unroll
        for (int bt = 0; bt < 4; ++bt)
#pragma unroll
            for (int r = 0; r < 4; ++r) {
                const float rr = fast_sigmoid(acc[bt][cgl * 3 + 0][r] + bir + bhr);
                const float zz = fast_sigmoid(acc[bt][cgl * 3 + 1][r] + biz + bhz);
                const float nn = fast_tanh(acc[bt][cgl * 3 + 2][r] + bin + rr * bhn);
                pl[bt][r] += (1.f - zz) * nn * dwg;
            }
    }
#pragma unroll
    for (int bt = 0; bt < 4; ++bt)
#pragma unroll
        for (int r = 0; r < 4; ++r)
            part[bt * 16 + rg * 4 + r][w * 16 + cl] = pl[bt][r];
    __syncthreads();

    // ---- deterministic margin reduce + decision + boundary append ----
    if (tid < 64) {
        float s = 0.f;
#pragma unroll
        for (int t = 0; t < 64; ++t) s += part[tid][t];
        const int b = b0 + tid;
        const float dbg = bg[pb * 2 + 1] - bg[pb * 2 + 0];
        const float* gp2 = gum + ((size_t)(b * NAG + pi) * NAG + pj) * 2;
        const float margin = s + dbg + (gp2[1] - gp2[0]);
        wout[(b * NAG + pi) * NAG + pj] = (margin > 0.f) ? 1.f : 0.f;
        if (fabsf(margin) < TAU) {
            const int idx = atomicAdd(counter, 1);
            if (idx < CAP) list[idx] = (b << 6) | (pi << 3) | pj;
        }
    }
}

// ============================================================ B2: exact-f32 refinement (v2)
// One WAVE per entry. Per iteration t the wave's 64 lanes read ONE contiguous
// 1KB slab of Wi = gate rows {2t, 2t+1} (fully coalesced float4), dot against
// u staged in LDS, shfl-reduce per 32-lane half -> per-gate totals in LDS.
// Old version: lane-strided rows -> 192 scattered 16B loads/lane, VALUBusy 8%,
// 169us. Uniform trip count per block so __syncthreads is safe.
__global__ __launch_bounds__(256) void refine_kernel(
    const float* __restrict__ h, const float* __restrict__ Wi,
    const float* __restrict__ bi, const float* __restrict__ bh,
    const float* __restrict__ Wg, const float* __restrict__ bg,
    const float* __restrict__ gum, const int* __restrict__ list,
    const int* __restrict__ counter, float* __restrict__ wout)
{
    __shared__ float u_sh[4][128];      // per-wave u = [h_i ; h_j]
    __shared__ float g_sh[4][384];      // per-wave per-gate dot totals

    const int tid = threadIdx.x;
    const int w   = tid >> 6;           // wave in block
    const int l   = tid & 63;
    const int nw4 = gridDim.x * 4;
    int count = counter[0]; if (count > CAP) count = CAP;

    for (int base = blockIdx.x * 4; base < count; base += nw4) {
        const int  e   = base + w;
        const bool act = (e < count);
        int code = act ? list[e] : 0;
        const int b   = code >> 6, pi2 = (code >> 3) & 7, pj2 = code & 7;
        const int pb  = pi2 * NAG + pj2;
        const float* Wr = Wi + (size_t)pb * 384 * GH;

        // ---- stage u into LDS (lanes 0..31: one float4 each) ----
        if (act && l < 32) {
            const float* src = (l < 16)
                ? h + ((size_t)b * NAG + pi2) * HD + l * 4
                : h + ((size_t)b * NAG + pj2) * HD + (l - 16) * 4;
            *reinterpret_cast<float4*>(&u_sh[w][l * 4]) =
                *reinterpret_cast<const float4*>(src);
        }
        __syncthreads();

        if (act) {
            const float4 uv = *reinterpret_cast<const float4*>(
                &u_sh[w][(l & 31) * 4]);          // lane's k-chunk (reused all t)
#pragma unroll 4
            for (int t = 0; t < 192; ++t) {
                // rows 2t,2t+1 = contiguous 256 floats; lane l -> float4 #l
                const float4 wv = *reinterpret_cast<const float4*>(
                    Wr + (size_t)t * 256 + l * 4);
                float p = wv.x * uv.x + wv.y * uv.y + wv.z * uv.z + wv.w * uv.w;
#pragma unroll
                for (int m = 1; m < 32; m <<= 1) p += __shfl_xor(p, m, 64);
                if ((l & 31) == 0) g_sh[w][2 * t + (l >> 5)] = p;
            }
        }
        __syncthreads();

        // ---- GRU epilogue: lane l handles channels c0, c0+1 ----
        if (act) {
            const int c0 = l * 2;
            const float* bip = bi + pb * 384;
            const float* bhp = bh + pb * 384;
            const float* wgp = Wg + pb * 256;
            const float2 gr = *reinterpret_cast<const float2*>(&g_sh[w][c0]);
            const float2 gz = *reinterpret_cast<const float2*>(&g_sh[w][128 + c0]);
            const float2 gn = *reinterpret_cast<const float2*>(&g_sh[w][256 + c0]);
            const float2 bir = *reinterpret_cast<const float2*>(&bip[c0]);
            const float2 biz = *reinterpret_cast<const float2*>(&bip[128 + c0]);
            const float2 bin = *reinterpret_cast<const float2*>(&bip[256 + c0]);
            const float2 bhr = *reinterpret_cast<const float2*>(&bhp[c0]);
            const float2 bhz = *reinterpret_cast<const float2*>(&bhp[128 + c0]);
            const float2 bhn = *reinterpret_cast<const float2*>(&bhp[256 + c0]);
            const float2 wg0 = *reinterpret_cast<const float2*>(&wgp[c0]);
            const float2 wg1 = *reinterpret_cast<const float2*>(&wgp[128 + c0]);

            float pl = 0.f;
            {
                const float r = fast_sigmoid(gr.x + bir.x + bhr.x);
                const float z = fast_sigmoid(gz.x + biz.x + bhz.x);
                const float n = fast_tanh(gn.x + bin.x + r * bhn.x);
                pl += (1.f - z) * n * (wg1.x - wg0.x);
            }
            {
                const float r = fast_sigmoid(gr.y + bir.y + bhr.y);
                const float z = fast_sigmoid(gz.y + biz.y + bhz.y);
                const float n = fast_tanh(gn.y + bin.y + r * bhn.y);
                pl += (1.f - z) * n * (wg1.y - wg0.y);
            }
#pragma unroll
            for (int m = 1; m < 64; m <<= 1) pl += __shfl_xor(pl, m, 64);
            if (l == 0) {
                const float dbg = bg[pb * 2 + 1] - bg[pb * 2 + 0];
                const float* gp2 = gum + ((size_t)(b * NAG + pi2) * NAG + pj2) * 2;
                const float margin = pl + dbg + (gp2[1] - gp2[0]);
                wout[(b * NAG + pi2) * NAG + pj2] = (margin > 0.f) ? 1.f : 0.f;
            }
        }
    }
}

// ============================================================ C: aggregate + decode
__global__ __launch_bounds__(256, 2) void agg_kernel(
    const float* __restrict__ h, const float* __restrict__ w,
    const float* __restrict__ Wd, const float* __restrict__ bd,
    float* __restrict__ q)
{
    const int b0 = blockIdx.x * 8;
    __shared__ float hl[8 * 520];
    const int tid = threadIdx.x;
#pragma unroll
    for (int p = 0; p < 4; ++p) {
        const int f = tid + p * 256;
        const int r = f >> 7, cc = (f & 127) * 4;
        *reinterpret_cast<float4*>(&hl[r * 520 + cc]) =
            *reinterpret_cast<const float4*>(&h[(size_t)b0 * 512 + f * 4]);
    }
    __syncthreads();

    const int aq = tid & 3;
    const int i  = (tid >> 2) & 7;
    const int bb = tid >> 5;
    const int b  = b0 + bb;

    float other[HD];
#pragma unroll
    for (int c = 0; c < HD; ++c) other[c] = 0.f;
    const float* wrow = w + ((size_t)b * NAG + i) * NAG;
    for (int j = 0; j < NAG; ++j) {
        if (j == i) continue;
        const float wv = wrow[j];
        const float* hr = &hl[bb * 520 + j * 64];
#pragma unroll
        for (int c4 = 0; c4 < HD / 4; ++c4) {
            const float4 v = *reinterpret_cast<const float4*>(hr + c4 * 4);
            other[c4*4+0] += wv * v.x; other[c4*4+1] += wv * v.y;
            other[c4*4+2] += wv * v.z; other[c4*4+3] += wv * v.w;
        }
    }
    const float* hi = &hl[bb * 520 + i * 64];
    const float* __restrict__ Wdp = Wd + (i * NACT) * (2 * HD);
    float qo[4];
#pragma unroll
    for (int t = 0; t < 4; ++t) {
        const int a = aq * 4 + t;
        float acc0 = bd[i * NACT + a];
        const float* wr = Wdp + a * 2 * HD;
#pragma unroll
        for (int c4 = 0; c4 < HD / 4; ++c4) {
            const float4 w1 = *reinterpret_cast<const float4*>(wr + c4 * 4);
            const float4 w2 = *reinterpret_cast<const float4*>(wr + 64 + c4 * 4);
            acc0 += hi[c4*4+0] * w1.x + hi[c4*4+1] * w1.y
                  + hi[c4*4+2] * w1.z + hi[c4*4+3] * w1.w
                  + other[c4*4+0] * w2.x + other[c4*4+1] * w2.y
                  + other[c4*4+2] * w2.z + other[c4*4+3] * w2.w;
        }
        qo[t] = acc0;
    }
    float4 qv = {qo[0], qo[1], qo[2], qo[3]};
    *reinterpret_cast<float4*>(&q[((size_t)b * NAG + i) * NACT + aq * 4]) = qv;
}

// ============================================================ launch
// ws layout (float units):
//   h @ 0 (8MB) | w @ 2,097,152 (1MB) | hb @ 2,359,296 (4MB)
//   wib @ 3,407,872 (6MB) | list @ 4,980,736 (256KB) | cnt @ 5,046,272
extern "C" void kernel_launch(void* const* d_in, const int* in_sizes, int n_in,
                              void* d_out, int out_size, void* d_ws, size_t ws_size,
                              hipStream_t stream) {
    const float* obs = (const float*)d_in[0];
    const float* gum = (const float*)d_in[1];
    const float* W1  = (const float*)d_in[2];
    const float* b1  = (const float*)d_in[3];
    const float* W2  = (const float*)d_in[4];
    const float* b2  = (const float*)d_in[5];
    const float* Wi  = (const float*)d_in[6];
    const float* bi  = (const float*)d_in[7];
    const float* bh  = (const float*)d_in[8];
    const float* Wg  = (const float*)d_in[9];
    const float* bg  = (const float*)d_in[10];
    const float* Wd  = (const float*)d_in[11];
    const float* bd  = (const float*)d_in[12];
    float* q = (float*)d_out;

    float*          ws   = (float*)d_ws;
    float*          h    = ws;
    float*          w    = ws + 2097152;
    unsigned short* hb   = (unsigned short*)(ws + 2359296);
    unsigned short* wib  = (unsigned short*)(ws + 3407872);
    int*            list = (int*)(ws + 4980736);
    int*            cnt  = (int*)(ws + 5046272);

    hipLaunchKernelGGL(zero_counter, dim3(1), dim3(64), 0, stream, cnt);
    hipLaunchKernelGGL(wiconv_kernel, dim3(1344), dim3(256), 0, stream, Wi, wib);
    hipLaunchKernelGGL(encode_kernel, dim3(NAG * (BATCH / 64)), dim3(256), 0, stream,
                       obs, W1, b1, W2, b2, h, hb);
    hipLaunchKernelGGL(pair_mfma_kernel, dim3(56 * 64), dim3(256), 0, stream,
                       hb, wib, bi, bh, Wg, bg, gum, w, list, cnt);
    hipLaunchKernelGGL(refine_kernel, dim3(512), dim3(256), 0, stream,
                       h, Wi, bi, bh, Wg, bg, gum, list, cnt, w);
    hipLaunchKernelGGL(agg_kernel, dim3(BATCH / 8), dim3(256), 0, stream,
                       h, w, Wd, bd, q);
}

// Round 8
// 290.308 us; speedup vs baseline: 1.6863x; 1.6863x over previous
//
#include <hip/hip_runtime.h>

#define BATCH 4096
#define NAG   8
#define OBS   64
#define HD    64
#define GH    128
#define NACT  16
#define TAU   0.05f
#define CAP   65536

typedef short  bf16x8 __attribute__((ext_vector_type(8)));
typedef unsigned short u16x8 __attribute__((ext_vector_type(8)));
typedef float  f32x4  __attribute__((ext_vector_type(4)));

// ============================================================ helpers
__device__ __forceinline__ float fast_sigmoid(float x) {
    return 1.f / (1.f + __expf(-x));
}
__device__ __forceinline__ float fast_tanh(float x) {
    x = fminf(fmaxf(x, -15.f), 15.f);
    const float e = __expf(2.f * x);
    return (e - 1.f) / (e + 1.f);
}
__device__ __forceinline__ unsigned short f2bf(float f) {   // RNE f32->bf16
    unsigned int u = __builtin_bit_cast(unsigned int, f);
    u = (u + 0x7FFFu + ((u >> 16) & 1u)) >> 16;
    return (unsigned short)u;
}

// ============================================================ counter zero
__global__ void zero_counter(int* c) { if (threadIdx.x == 0) c[0] = 0; }

// ============================================================ Wi -> bf16, gate-permuted
// out gate index g' = cg*48 + s*16 + cl  <- src gate g = s*128 + cg*16 + cl.
__global__ __launch_bounds__(256) void wiconv_kernel(
    const float* __restrict__ Wi, unsigned short* __restrict__ wib)
{
    const int t   = blockIdx.x * 256 + threadIdx.x;   // 0..344063
    const int pp  = t / 6144;                         // 56 off-diag pairs
    const int rem = t - pp * 6144;
    const int gp  = rem >> 4;                         // 0..383
    const int k8  = rem & 15;                         // 8-elem chunk along k
    const int pi  = pp / 7;
    int pj = pp % 7; pj += (pj >= pi);
    const int pb  = pi * NAG + pj;
    const int cg  = gp / 48;
    const int r2  = gp - cg * 48;
    const int s   = r2 >> 4, cl = r2 & 15;
    const int g   = s * GH + cg * 16 + cl;
    const float* src = Wi + ((size_t)pb * 384 + g) * GH + k8 * 8;
    u16x8 o;
#pragma unroll
    for (int e = 0; e < 8; ++e) o[e] = f2bf(src[e]);
    *reinterpret_cast<u16x8*>(wib + ((size_t)pb * 384 + gp) * GH + k8 * 8) = o;
}

// ============================================================ A: encode (+ bf16 mirror)
__global__ __launch_bounds__(256, 2) void encode_kernel(
    const float* __restrict__ obs, const float* __restrict__ W1,
    const float* __restrict__ b1, const float* __restrict__ W2,
    const float* __restrict__ b2, float* __restrict__ h,
    unsigned short* __restrict__ hb)
{
    const int n    = blockIdx.x >> 6;
    const int tile = blockIdx.x & 63;
    const int b0   = tile * 64;
    const int tid  = threadIdx.x;

    __shared__ float u1[OBS * 68];
    __shared__ float h1t[GH * 68];
    __shared__ float wl[16 * GH];

    const float* __restrict__ W1n = W1 + n * (OBS * GH);
    const float* __restrict__ W2n = W2 + n * (GH * HD);
    const float* __restrict__ b1n = b1 + n * GH;
    const float* __restrict__ b2n = b2 + n * HD;

    {
        const int c  = tid & 63;
        const int r0 = tid >> 6;
        for (int rr = 0; rr < 16; ++rr) {
            const int bb = r0 * 16 + rr;
            u1[c * 68 + bb] = obs[((size_t)(b0 + bb) * NAG + n) * OBS + c];
        }
    }

    const int bq = tid & 15;
    const int cg = tid >> 4;

    float acc1[8][4];
#pragma unroll
    for (int cc = 0; cc < 8; ++cc)
#pragma unroll
        for (int bb = 0; bb < 4; ++bb) acc1[cc][bb] = 0.f;

    for (int kc = 0; kc < 4; ++kc) {
        __syncthreads();
#pragma unroll
        for (int p = 0; p < 2; ++p) {
            const int f = tid + p * 256;
            const int k = f >> 5, c4 = f & 31;
            *reinterpret_cast<float4*>(&wl[k * GH + c4 * 4]) =
                *reinterpret_cast<const float4*>(&W1n[(kc * 16 + k) * GH + c4 * 4]);
        }
        __syncthreads();
#pragma unroll 2
        for (int k = 0; k < 16; ++k) {
            const float4 uu = *reinterpret_cast<const float4*>(
                &u1[(kc * 16 + k) * 68 + bq * 4]);
            const float ub[4] = {uu.x, uu.y, uu.z, uu.w};
            const float4 wa = *reinterpret_cast<const float4*>(&wl[k * GH + cg * 8]);
            const float4 wb = *reinterpret_cast<const float4*>(&wl[k * GH + cg * 8 + 4]);
            const float wv[8] = {wa.x, wa.y, wa.z, wa.w, wb.x, wb.y, wb.z, wb.w};
#pragma unroll
            for (int cc = 0; cc < 8; ++cc)
#pragma unroll
                for (int bb = 0; bb < 4; ++bb)
                    acc1[cc][bb] += wv[cc] * ub[bb];
        }
    }

    {
        const float4 ba  = *reinterpret_cast<const float4*>(&b1n[cg * 8]);
        const float4 bb4 = *reinterpret_cast<const float4*>(&b1n[cg * 8 + 4]);
        const float bv[8] = {ba.x, ba.y, ba.z, ba.w, bb4.x, bb4.y, bb4.z, bb4.w};
#pragma unroll
        for (int cc = 0; cc < 8; ++cc)
#pragma unroll
            for (int bb = 0; bb < 4; ++bb)
                h1t[(cg * 8 + cc) * 68 + bq * 4 + bb] =
                    fmaxf(acc1[cc][bb] + bv[cc], 0.f);
    }

    const int og = tid >> 4;
    float acc2[4][4];
#pragma unroll
    for (int oc = 0; oc < 4; ++oc)
#pragma unroll
        for (int bb = 0; bb < 4; ++bb) acc2[oc][bb] = 0.f;

    for (int kc = 0; kc < 8; ++kc) {
        __syncthreads();
        {
            const int k = tid >> 4, o4 = tid & 15;
            *reinterpret_cast<float4*>(&wl[k * HD + o4 * 4]) =
                *reinterpret_cast<const float4*>(&W2n[(kc * 16 + k) * HD + o4 * 4]);
        }
        __syncthreads();
#pragma unroll 2
        for (int k = 0; k < 16; ++k) {
            const float4 uu = *reinterpret_cast<const float4*>(
                &h1t[(kc * 16 + k) * 68 + bq * 4]);
            const float ub[4] = {uu.x, uu.y, uu.z, uu.w};
            const float4 wa = *reinterpret_cast<const float4*>(&wl[k * HD + og * 4]);
            const float wv[4] = {wa.x, wa.y, wa.z, wa.w};
#pragma unroll
            for (int oc = 0; oc < 4; ++oc)
#pragma unroll
                for (int bb = 0; bb < 4; ++bb)
                    acc2[oc][bb] += wv[oc] * ub[bb];
        }
    }

    {
        const float4 b2v = *reinterpret_cast<const float4*>(&b2n[og * 4]);
#pragma unroll
        for (int bb = 0; bb < 4; ++bb) {
            float4 o;
            o.x = fmaxf(acc2[0][bb] + b2v.x, 0.f);
            o.y = fmaxf(acc2[1][bb] + b2v.y, 0.f);
            o.z = fmaxf(acc2[2][bb] + b2v.z, 0.f);
            o.w = fmaxf(acc2[3][bb] + b2v.w, 0.f);
            const size_t row = (size_t)(b0 + bq * 4 + bb) * NAG + n;
            *reinterpret_cast<float4*>(&h[row * HD + og * 4]) = o;
            ushort4 hv;
            hv.x = f2bf(o.x); hv.y = f2bf(o.y); hv.z = f2bf(o.z); hv.w = f2bf(o.w);
            *reinterpret_cast<ushort4*>(&hb[row * HD + og * 4]) = hv;
        }
    }
}

// ============================================================ B: pairwise GRU via MFMA
// (unchanged from R5/R6 — validated: absmax held at 0.0078, no gate flips)
__global__ __launch_bounds__(256, 2) void pair_mfma_kernel(
    const unsigned short* __restrict__ hb, const unsigned short* __restrict__ wib,
    const float* __restrict__ bi, const float* __restrict__ bh,
    const float* __restrict__ Wg, const float* __restrict__ bg,
    const float* __restrict__ gum, float* __restrict__ wout,
    int* __restrict__ list, int* __restrict__ counter)
{
    const int pairp = blockIdx.x >> 6;
    const int tile  = blockIdx.x & 63;
    const int pi = pairp / 7;
    int pj = pairp % 7; pj += (pj >= pi);
    const int pb = pi * NAG + pj;
    const int b0 = tile * 64;

    const int tid = threadIdx.x;
    const int w   = tid >> 6;          // wave 0..3
    const int l   = tid & 63;
    const int cl  = l & 15;            // A: batch row offset / B,D: column
    const int rg  = l >> 4;            // k-chunk group / D row group

    f32x4 acc[4][6];
#pragma unroll
    for (int bt = 0; bt < 4; ++bt)
#pragma unroll
        for (int t = 0; t < 6; ++t) acc[bt][t] = (f32x4){0.f, 0.f, 0.f, 0.f};

#pragma unroll
    for (int kb = 0; kb < 4; ++kb) {
        const int ag = (kb < 2) ? pi : pj;          // u = [h_i ; h_j]
        const int ch = (kb & 1) * 32 + rg * 8;      // channel chunk within agent
        bf16x8 av[4];
#pragma unroll
        for (int bt = 0; bt < 4; ++bt) {
            const int b = b0 + bt * 16 + cl;
            av[bt] = *reinterpret_cast<const bf16x8*>(
                &hb[((size_t)b * NAG + ag) * HD + ch]);
        }
        const size_t wbase = ((size_t)pb * 384 + w * 96 + cl) * GH + kb * 32 + rg * 8;
#pragma unroll
        for (int t = 0; t < 6; ++t) {
            const bf16x8 bv = *reinterpret_cast<const bf16x8*>(
                &wib[wbase + (size_t)t * 16 * GH]);
#pragma unroll
            for (int bt = 0; bt < 4; ++bt)
                acc[bt][t] = __builtin_amdgcn_mfma_f32_16x16x32_bf16(
                    av[bt], bv, acc[bt][t], 0, 0, 0);
        }
    }

    // ---- GRU epilogue: t = cgl*3 + s; channel c = (2w+cgl)*16 + cl ----
    __shared__ float part[64][68];
    float pl[4][4];
#pragma unroll
    for (int bt = 0; bt < 4; ++bt)
#pragma unroll
        for (int r = 0; r < 4; ++r) pl[bt][r] = 0.f;

#pragma unroll
    for (int cgl = 0; cgl < 2; ++cgl) {
        const int c = (2 * w + cgl) * 16 + cl;
        const float bir = bi[pb * 384 + c];
        const float biz = bi[pb * 384 + 128 + c];
        const float bin = bi[pb * 384 + 256 + c];
        const float bhr = bh[pb * 384 + c];
        const float bhz = bh[pb * 384 + 128 + c];
        const float bhn = bh[pb * 384 + 256 + c];
        const float dwg = Wg[pb * 256 + 128 + c] - Wg[pb * 256 + c];
#pragma unroll
        for (int bt = 0; bt < 4; ++bt)
#pragma unroll
            for (int r = 0; r < 4; ++r) {
                const float rr = fast_sigmoid(acc[bt][cgl * 3 + 0][r] + bir + bhr);
                const float zz = fast_sigmoid(acc[bt][cgl * 3 + 1][r] + biz + bhz);
                const float nn = fast_tanh(acc[bt][cgl * 3 + 2][r] + bin + rr * bhn);
                pl[bt][r] += (1.f - zz) * nn * dwg;
            }
    }
#pragma unroll
    for (int bt = 0; bt < 4; ++bt)
#pragma unroll
        for (int r = 0; r < 4; ++r)
            part[bt * 16 + rg * 4 + r][w * 16 + cl] = pl[bt][r];
    __syncthreads();

    // ---- deterministic margin reduce + decision + boundary append ----
    if (tid < 64) {
        float s = 0.f;
#pragma unroll
        for (int t = 0; t < 64; ++t) s += part[tid][t];
        const int b = b0 + tid;
        const float dbg = bg[pb * 2 + 1] - bg[pb * 2 + 0];
        const float* gp2 = gum + ((size_t)(b * NAG + pi) * NAG + pj) * 2;
        const float margin = s + dbg + (gp2[1] - gp2[0]);
        wout[(b * NAG + pi) * NAG + pj] = (margin > 0.f) ? 1.f : 0.f;
        if (fabsf(margin) < TAU) {
            const int idx = atomicAdd(counter, 1);
            if (idx < CAP) list[idx] = (b << 6) | (pi << 3) | pj;
        }
    }
}

// ============================================================ B2: exact-f32 refinement (v3)
// One BLOCK per entry (grid-stride). Thread L = (row-slot L>>3, f4-slot L&7):
// 12 rows/thread, 4 coalesced float4 loads each (8 lanes cover a 128B row
// segment), LANE-PRIVATE partial accumulation -> one LDS scatter part[384][9].
// v2's bug: a 5-step __shfl_xor chain per inner iteration (192x) = ~24K cycles
// of serial cross-lane latency per entry (VALUBusy 7%, 252us). v3 has zero
// cross-lane ops in the hot loop; one 6-step shuffle per ENTRY at the end.
// Floor: ~5.7K entries x 196KB Wi = 1.1GB L2 traffic ~= 33us at L2 BW.
__global__ __launch_bounds__(256) void refine_kernel(
    const float* __restrict__ h, const float* __restrict__ Wi,
    const float* __restrict__ bi, const float* __restrict__ bh,
    const float* __restrict__ Wg, const float* __restrict__ bg,
    const float* __restrict__ gum, const int* __restrict__ list,
    const int* __restrict__ counter, float* __restrict__ wout)
{
    __shared__ float u_sh[128];         // u = [h_i ; h_j]
    __shared__ float part[384 * 9];     // per-gate partials, padded stride 9
    __shared__ float pl_sh[128];        // per-channel logit contributions

    const int tid = threadIdx.x;
    const int rs  = tid >> 3;           // row slot 0..31
    const int fs  = tid & 7;            // float4 slot 0..7
    int count = counter[0]; if (count > CAP) count = CAP;

    for (int e = blockIdx.x; e < count; e += gridDim.x) {
        const int code = list[e];
        const int b = code >> 6, pi2 = (code >> 3) & 7, pj2 = code & 7;
        const int pb = pi2 * NAG + pj2;
        const float* __restrict__ Wr = Wi + (size_t)pb * 384 * GH;

        if (tid < 32) {
            const float* src = (tid < 16)
                ? h + ((size_t)b * NAG + pi2) * HD + tid * 4
                : h + ((size_t)b * NAG + pj2) * HD + (tid - 16) * 4;
            *reinterpret_cast<float4*>(&u_sh[tid * 4]) =
                *reinterpret_cast<const float4*>(src);
        }
        __syncthreads();

        float4 uv[4];
#pragma unroll
        for (int s = 0; s < 4; ++s)
            uv[s] = *reinterpret_cast<const float4*>(&u_sh[(fs + 8 * s) * 4]);

#pragma unroll 2
        for (int si = 0; si < 12; ++si) {
            const int r = si * 32 + rs;
            const float* row = Wr + (size_t)r * GH;
            float p = 0.f;
#pragma unroll
            for (int s = 0; s < 4; ++s) {
                const float4 wv = *reinterpret_cast<const float4*>(
                    row + (fs + 8 * s) * 4);
                p += wv.x * uv[s].x + wv.y * uv[s].y
                   + wv.z * uv[s].z + wv.w * uv[s].w;
            }
            part[r * 9 + fs] = p;
        }
        __syncthreads();

        // ---- per-channel GRU: thread c in [0,128) ----
        if (tid < 128) {
            const int c = tid;
            float gr = 0.f, gz = 0.f, gn = 0.f;
#pragma unroll
            for (int k = 0; k < 8; ++k) {
                gr += part[c * 9 + k];
                gz += part[(128 + c) * 9 + k];
                gn += part[(256 + c) * 9 + k];
            }
            const float r = fast_sigmoid(gr + bi[pb*384 + c] + bh[pb*384 + c]);
            const float z = fast_sigmoid(gz + bi[pb*384 + 128 + c] + bh[pb*384 + 128 + c]);
            const float n = fast_tanh(gn + bi[pb*384 + 256 + c]
                                      + r * bh[pb*384 + 256 + c]);
            pl_sh[c] = (1.f - z) * n * (Wg[pb*256 + 128 + c] - Wg[pb*256 + c]);
        }
        __syncthreads();

        if (tid < 64) {
            float p = pl_sh[tid] + pl_sh[tid + 64];
#pragma unroll
            for (int m = 1; m < 64; m <<= 1) p += __shfl_xor(p, m, 64);
            if (tid == 0) {
                const float dbg = bg[pb * 2 + 1] - bg[pb * 2 + 0];
                const float* gp2 = gum + ((size_t)(b * NAG + pi2) * NAG + pj2) * 2;
                const float margin = p + dbg + (gp2[1] - gp2[0]);
                wout[(b * NAG + pi2) * NAG + pj2] = (margin > 0.f) ? 1.f : 0.f;
            }
        }
        __syncthreads();   // all reads done before next entry's stores
    }
}

// ============================================================ C: aggregate + decode
__global__ __launch_bounds__(256, 2) void agg_kernel(
    const float* __restrict__ h, const float* __restrict__ w,
    const float* __restrict__ Wd, const float* __restrict__ bd,
    float* __restrict__ q)
{
    const int b0 = blockIdx.x * 8;
    __shared__ float hl[8 * 520];
    const int tid = threadIdx.x;
#pragma unroll
    for (int p = 0; p < 4; ++p) {
        const int f = tid + p * 256;
        const int r = f >> 7, cc = (f & 127) * 4;
        *reinterpret_cast<float4*>(&hl[r * 520 + cc]) =
            *reinterpret_cast<const float4*>(&h[(size_t)b0 * 512 + f * 4]);
    }
    __syncthreads();

    const int aq = tid & 3;
    const int i  = (tid >> 2) & 7;
    const int bb = tid >> 5;
    const int b  = b0 + bb;

    float other[HD];
#pragma unroll
    for (int c = 0; c < HD; ++c) other[c] = 0.f;
    const float* wrow = w + ((size_t)b * NAG + i) * NAG;
    for (int j = 0; j < NAG; ++j) {
        if (j == i) continue;
        const float wv = wrow[j];
        const float* hr = &hl[bb * 520 + j * 64];
#pragma unroll
        for (int c4 = 0; c4 < HD / 4; ++c4) {
            const float4 v = *reinterpret_cast<const float4*>(hr + c4 * 4);
            other[c4*4+0] += wv * v.x; other[c4*4+1] += wv * v.y;
            other[c4*4+2] += wv * v.z; other[c4*4+3] += wv * v.w;
        }
    }
    const float* hi = &hl[bb * 520 + i * 64];
    const float* __restrict__ Wdp = Wd + (i * NACT) * (2 * HD);
    float qo[4];
#pragma unroll
    for (int t = 0; t < 4; ++t) {
        const int a = aq * 4 + t;
        float acc0 = bd[i * NACT + a];
        const float* wr = Wdp + a * 2 * HD;
#pragma unroll
        for (int c4 = 0; c4 < HD / 4; ++c4) {
            const float4 w1 = *reinterpret_cast<const float4*>(wr + c4 * 4);
            const float4 w2 = *reinterpret_cast<const float4*>(wr + 64 + c4 * 4);
            acc0 += hi[c4*4+0] * w1.x + hi[c4*4+1] * w1.y
                  + hi[c4*4+2] * w1.z + hi[c4*4+3] * w1.w
                  + other[c4*4+0] * w2.x + other[c4*4+1] * w2.y
                  + other[c4*4+2] * w2.z + other[c4*4+3] * w2.w;
        }
        qo[t] = acc0;
    }
    float4 qv = {qo[0], qo[1], qo[2], qo[3]};
    *reinterpret_cast<float4*>(&q[((size_t)b * NAG + i) * NACT + aq * 4]) = qv;
}

// ============================================================ launch
// ws layout (float units):
//   h @ 0 (8MB) | w @ 2,097,152 (1MB) | hb @ 2,359,296 (4MB)
//   wib @ 3,407,872 (6MB) | list @ 4,980,736 (256KB) | cnt @ 5,046,272
extern "C" void kernel_launch(void* const* d_in, const int* in_sizes, int n_in,
                              void* d_out, int out_size, void* d_ws, size_t ws_size,
                              hipStream_t stream) {
    const float* obs = (const float*)d_in[0];
    const float* gum = (const float*)d_in[1];
    const float* W1  = (const float*)d_in[2];
    const float* b1  = (const float*)d_in[3];
    const float* W2  = (const float*)d_in[4];
    const float* b2  = (const float*)d_in[5];
    const float* Wi  = (const float*)d_in[6];
    const float* bi  = (const float*)d_in[7];
    const float* bh  = (const float*)d_in[8];
    const float* Wg  = (const float*)d_in[9];
    const float* bg  = (const float*)d_in[10];
    const float* Wd  = (const float*)d_in[11];
    const float* bd  = (const float*)d_in[12];
    float* q = (float*)d_out;

    float*          ws   = (float*)d_ws;
    float*          h    = ws;
    float*          w    = ws + 2097152;
    unsigned short* hb   = (unsigned short*)(ws + 2359296);
    unsigned short* wib  = (unsigned short*)(ws + 3407872);
    int*            list = (int*)(ws + 4980736);
    int*            cnt  = (int*)(ws + 5046272);

    hipLaunchKernelGGL(zero_counter, dim3(1), dim3(64), 0, stream, cnt);
    hipLaunchKernelGGL(wiconv_kernel, dim3(1344), dim3(256), 0, stream, Wi, wib);
    hipLaunchKernelGGL(encode_kernel, dim3(NAG * (BATCH / 64)), dim3(256), 0, stream,
                       obs, W1, b1, W2, b2, h, hb);
    hipLaunchKernelGGL(pair_mfma_kernel, dim3(56 * 64), dim3(256), 0, stream,
                       hb, wib, bi, bh, Wg, bg, gum, w, list, cnt);
    hipLaunchKernelGGL(refine_kernel, dim3(2048), dim3(256), 0, stream,
                       h, Wi, bi, bh, Wg, bg, gum, list, cnt, w);
    hipLaunchKernelGGL(agg_kernel, dim3(BATCH / 8), dim3(256), 0, stream,
                       h, w, Wd, bd, q);
}